// Round 3
// baseline (158.465 us; speedup 1.0000x reference)
//
#include <hip/hip_runtime.h>

typedef unsigned short u16;
typedef __bf16 v8bf __attribute__((ext_vector_type(8)));
typedef float f32x4 __attribute__((ext_vector_type(4)));
typedef u16 us8 __attribute__((ext_vector_type(8)));
typedef u16 us4 __attribute__((ext_vector_type(4)));

static __device__ __forceinline__ u16 f2bf(float f) {
  union { __bf16 h; u16 u; } cv;
  cv.h = (__bf16)f;
  return cv.u;
}

static __device__ __forceinline__ void gl_lds16(const u16* g, u16* l) {
  __builtin_amdgcn_global_load_lds(
      (const __attribute__((address_space(1))) unsigned int*)g,
      (__attribute__((address_space(3))) unsigned int*)l, 16, 0, 0);
}

// ---- adj fp32->bf16 (blocks 0..2047) + fold W (block 2048) ----
__global__ __launch_bounds__(256)
void cvt_adj_foldw_k(const float* __restrict__ adj, u16* __restrict__ adj_bf,
                     const float* __restrict__ W, u16* __restrict__ Mb) {
  if (blockIdx.x < 2048) {
    const int i = blockIdx.x * 256 + threadIdx.x;  // < 524288 = 16*512*512/8
    const float4 a = ((const float4*)adj)[2 * i];
    const float4 b = ((const float4*)adj)[2 * i + 1];
    us8 r;
    r[0] = f2bf(a.x); r[1] = f2bf(a.y); r[2] = f2bf(a.z); r[3] = f2bf(a.w);
    r[4] = f2bf(b.x); r[5] = f2bf(b.y); r[6] = f2bf(b.z); r[7] = f2bf(b.w);
    ((us8*)adj_bf)[i] = r;
  } else {
    for (int i = threadIdx.x; i < 64 * 96; i += 256) {
      const int cc = i % 96;
      const int r = cc % 3;
      const float w = W[i];
      const float m = (r == 0) ? (w - W[i + 2]) : ((r == 1) ? w : 2.0f * w);
      Mb[i] = f2bf(m);
    }
  }
}

// ---- x [b][q][c*64+l] fp32 -> x_bfT [b][j=c*64+l][q] bf16 (64x64 LDS transpose) ----
__global__ __launch_bounds__(256)
void cvtT_x_k(const float* __restrict__ x, u16* __restrict__ xT) {
  const int j0 = blockIdx.x * 64;
  const int q0 = blockIdx.y * 64;
  const int b = blockIdx.z;
  __shared__ u16 Ls[64][68];
  const int tid = threadIdx.x;
#pragma unroll
  for (int i = 0; i < 4; ++i) {
    const int idx = tid + 256 * i;          // 1024 float4 chunks
    const int r = idx >> 4;                 // q offset
    const int j4 = (idx & 15) * 4;
    const float4 v = *(const float4*)(x + ((size_t)(b * 512 + q0 + r) * 2048 + j0 + j4));
    us4 o;
    o[0] = f2bf(v.x); o[1] = f2bf(v.y); o[2] = f2bf(v.z); o[3] = f2bf(v.w);
    *(us4*)&Ls[r][j4] = o;
  }
  __syncthreads();
#pragma unroll
  for (int i = 0; i < 2; ++i) {
    const int idx = tid + 256 * i;          // 512 us8 chunks
    const int rp = idx >> 3;                // j offset
    const int q8 = (idx & 7) * 8;
    us8 o;
#pragma unroll
    for (int j = 0; j < 8; ++j) o[j] = Ls[q8 + j][rp];
    *(us8*)(xT + ((size_t)(b * 2048 + j0 + rp) * 512 + q0 + q8)) = o;
  }
}

// ---- C[b](512x2048) = A[b](512x512) @ B[b](512x2048); BT = [2048][512] k-major.
//      WT: also write CT[b] = C^T [2048][512]. m97-style: 128x128 tile, BK=64,
//      global_load_lds staging, 4 waves, 4x4 16x16x32 frags/wave. ----
template<bool WT>
__global__ __launch_bounds__(256)
void gemm_t(const u16* __restrict__ A, const u16* __restrict__ BT,
            u16* __restrict__ C, u16* __restrict__ CT) {
  const int b = blockIdx.z;
  const int row0 = blockIdx.y * 128;
  const int col0 = blockIdx.x * 128;
  const u16* Ab = A + (size_t)b * 512 * 512;
  const u16* BTb = BT + (size_t)b * 2048 * 512;

  __shared__ u16 smem[17408];  // 34816 B: staging 2x8192, reused as 128x136 transpose
  u16* As = smem;              // [128][64] linear
  u16* Bs = smem + 8192;       // [128][64] linear (row = output col)

  const int tid = threadIdx.x;
  const int lane = tid & 63;
  const int w = tid >> 6;
  const int wm = (w >> 1) * 64;
  const int wn = (w & 1) * 64;
  const int l16 = lane & 15;
  const int kg = lane >> 4;

  f32x4 acc[4][4];
#pragma unroll
  for (int m = 0; m < 4; ++m)
#pragma unroll
    for (int n = 0; n < 4; ++n) acc[m][n] = (f32x4){0.f, 0.f, 0.f, 0.f};

  for (int k0 = 0; k0 < 512; k0 += 64) {
    __syncthreads();
#pragma unroll
    for (int i = 0; i < 4; ++i) {
      const int eb = w * 2048 + i * 512;    // wave-uniform LDS elem base
      const int e = eb + lane * 8;
      const int r = e >> 6;
      const int kk = e & 63;
      gl_lds16(Ab + (size_t)(row0 + r) * 512 + k0 + kk, As + eb);
      gl_lds16(BTb + (size_t)(col0 + r) * 512 + k0 + kk, Bs + eb);
    }
    __syncthreads();
#pragma unroll
    for (int ks = 0; ks < 2; ++ks) {
      v8bf af[4], bfr[4];
#pragma unroll
      for (int m = 0; m < 4; ++m)
        af[m] = *(const v8bf*)(As + (wm + m * 16 + l16) * 64 + ks * 32 + kg * 8);
#pragma unroll
      for (int n = 0; n < 4; ++n)
        bfr[n] = *(const v8bf*)(Bs + (wn + n * 16 + l16) * 64 + ks * 32 + kg * 8);
#pragma unroll
      for (int m = 0; m < 4; ++m)
#pragma unroll
        for (int n = 0; n < 4; ++n)
          acc[m][n] = __builtin_amdgcn_mfma_f32_16x16x32_bf16(af[m], bfr[n], acc[m][n], 0, 0, 0);
    }
  }

  // normal C write (row-major [512][2048])
  u16* Cb = C + (size_t)b * 512 * 2048;
#pragma unroll
  for (int m = 0; m < 4; ++m)
#pragma unroll
    for (int n = 0; n < 4; ++n)
#pragma unroll
      for (int v = 0; v < 4; ++v) {
        const int rr = row0 + wm + m * 16 + kg * 4 + v;
        const int cc = col0 + wn + n * 16 + l16;
        Cb[(size_t)rr * 2048 + cc] = f2bf(acc[m][n][v]);
      }

  if constexpr (WT) {
    __syncthreads();  // all frag reads of smem done
    u16* Ctr = smem;  // [128][136]
#pragma unroll
    for (int m = 0; m < 4; ++m)
#pragma unroll
      for (int n = 0; n < 4; ++n)
#pragma unroll
        for (int v = 0; v < 4; ++v)
          Ctr[(wn + n * 16 + l16) * 136 + (wm + m * 16 + kg * 4 + v)] = f2bf(acc[m][n][v]);
    __syncthreads();
    u16* CTb = CT + (size_t)b * 2048 * 512;
#pragma unroll
    for (int i = 0; i < 8; ++i) {
      const int idx = tid + 256 * i;        // 2048 us8 chunks (128x128)
      const int jp = idx >> 4;              // local col of C = row of CT
      const int q8 = (idx & 15) * 8;        // local row of C
      const us8 o = *(const us8*)(Ctr + jp * 136 + q8);
      *(us8*)(CTb + (size_t)(col0 + jp) * 512 + row0 + q8) = o;
    }
  }
}

// ---- mix (identical to round 2): per (b,q): out[b,:,q,:] = M(64x96) @ V(96x64) + bias ----
__global__ __launch_bounds__(256)
void mix_mfma(const float* __restrict__ x0, const u16* __restrict__ x1,
              const u16* __restrict__ y2, const u16* __restrict__ Mb,
              const float* __restrict__ bias, float* __restrict__ out) {
  const int q = blockIdx.x;
  const int b = blockIdx.y;
  __shared__ u16 Vt[64][104];
  __shared__ u16 Ms[64][104];
  const int tid = threadIdx.x;
  const int lane = tid & 63;
  const int w = tid >> 6;
  const int l16 = lane & 15;
  const int kg = lane >> 4;

#pragma unroll
  for (int i = 0; i < 3; ++i) {
    const int idx = tid + 256 * i;
    const int o = idx / 12;
    const int c8 = (idx % 12) * 8;
    *(uint4*)&Ms[o][c8] = *(const uint4*)(Mb + o * 96 + c8);
  }
  const size_t base = ((size_t)b * 512 + q) * 2048;
#pragma unroll
  for (int i = 0; i < 2; ++i) {
    const int idx = tid + 256 * i;
    const int c = idx >> 4;
    const int l0 = (idx & 15) * 4;
    const float4 v = *(const float4*)(x0 + base + c * 64 + l0);
    Vt[l0 + 0][3 * c] = f2bf(v.x);
    Vt[l0 + 1][3 * c] = f2bf(v.y);
    Vt[l0 + 2][3 * c] = f2bf(v.z);
    Vt[l0 + 3][3 * c] = f2bf(v.w);
  }
  {
    const int c = tid >> 3;
    const int l0 = (tid & 7) * 8;
    const us8 v1 = *(const us8*)(x1 + base + c * 64 + l0);
    const us8 v2 = *(const us8*)(y2 + base + c * 64 + l0);
#pragma unroll
    for (int j = 0; j < 8; ++j) {
      Vt[l0 + j][3 * c + 1] = v1[j];
      Vt[l0 + j][3 * c + 2] = v2[j];
    }
  }
  __syncthreads();

  f32x4 acc[4];
#pragma unroll
  for (int n = 0; n < 4; ++n) acc[n] = (f32x4){0.f, 0.f, 0.f, 0.f};
#pragma unroll
  for (int ks = 0; ks < 3; ++ks) {
    const v8bf a = *(const v8bf*)&Ms[w * 16 + l16][ks * 32 + kg * 8];
#pragma unroll
    for (int n = 0; n < 4; ++n) {
      const v8bf bv = *(const v8bf*)&Vt[n * 16 + l16][ks * 32 + kg * 8];
      acc[n] = __builtin_amdgcn_mfma_f32_16x16x32_bf16(a, bv, acc[n], 0, 0, 0);
    }
  }
#pragma unroll
  for (int n = 0; n < 4; ++n)
#pragma unroll
    for (int v = 0; v < 4; ++v) {
      const int o = w * 16 + kg * 4 + v;
      out[(((size_t)b * 64 + o) * 512 + q) * 64 + n * 16 + l16] = acc[n][v] + bias[o];
    }
}

extern "C" void kernel_launch(void* const* d_in, const int* in_sizes, int n_in,
                              void* d_out, int out_size, void* d_ws, size_t ws_size,
                              hipStream_t stream) {
  const float* x   = (const float*)d_in[0];  // [16,512,32,64]
  const float* adj = (const float*)d_in[1];  // [16,512,512]
  const float* W   = (const float*)d_in[2];  // [64,96]
  const float* bia = (const float*)d_in[3];  // [64]
  float* out = (float*)d_out;                // [16,64,512,64]

  u16* adj_bf = (u16*)d_ws;                              //  8.4 MB
  u16* xT     = adj_bf + (size_t)16 * 512 * 512;         // [16][2048][512]
  u16* X1     = xT     + (size_t)16 * 2048 * 512;        // [16][512][2048]
  u16* X1T    = X1     + (size_t)16 * 512 * 2048;        // [16][2048][512]
  u16* Y2     = X1T    + (size_t)16 * 2048 * 512;        // [16][512][2048]
  u16* Mb     = Y2     + (size_t)16 * 512 * 2048;

  hipLaunchKernelGGL(cvt_adj_foldw_k, dim3(2049), dim3(256), 0, stream, adj, adj_bf, W, Mb);
  hipLaunchKernelGGL(cvtT_x_k, dim3(32, 8, 16), dim3(256), 0, stream, x, xT);

  dim3 gg(2048 / 128, 512 / 128, 16);  // (16, 4, 16)
  hipLaunchKernelGGL((gemm_t<true>), gg, dim3(256), 0, stream, adj_bf, xT, X1, X1T);
  hipLaunchKernelGGL((gemm_t<false>), gg, dim3(256), 0, stream, adj_bf, X1T, Y2, (u16*)nullptr);

  hipLaunchKernelGGL(mix_mfma, dim3(512, 16), dim3(256), 0, stream, x, X1, Y2, Mb, bia, out);
}